// Round 6
// baseline (550.872 us; speedup 1.0000x reference)
//
#include <hip/hip_runtime.h>
#include <cstdint>
#include <cstddef>

#define HEADS 8
#define DH 64
#define DIM 512      // HEADS*DH
#define CIN 256
#define EPS 1e-5f
#define NB 64        // token-blocks per (batch, head) in K1
#define BATCH 2
#define NTOK 32768   // 8*64*64 tokens (fixed problem size)

#define XPAD 264     // x / q-chunk LDS row stride in shorts (528B, 16B-aligned)
#define TP 40        // ekT/vT LDS row stride in shorts (80B, 16B-aligned)

// floats to zero ahead of K1: ctx_un (B*8*64*64) + Ssum (B*8*64), contiguous
#define ZERO_FLOATS (BATCH * HEADS * DH * DH + BATCH * HEADS * DH)   // 66560
#define ZERO_F4     (ZERO_FLOATS / 4)                                // 16640

typedef __attribute__((ext_vector_type(8))) short bf16x8;
typedef __attribute__((ext_vector_type(4))) float f32x4;

static __device__ __forceinline__ f32x4 mfma16(bf16x8 a, bf16x8 b, f32x4 c) {
  return __builtin_amdgcn_mfma_f32_16x16x32_bf16(a, b, c, 0, 0, 0);
}
static __device__ __forceinline__ unsigned short f2bf(float f) {
  unsigned int u = __float_as_uint(f);
  u += 0x7FFFu + ((u >> 16) & 1u);   // RNE (finite inputs only)
  return (unsigned short)(u >> 16);
}
static __device__ __forceinline__ float bf2f(unsigned short h) {
  return __uint_as_float(((unsigned int)h) << 16);
}
// split f ~= hi + lo, each bf16; residual ~2^-18 rel
static __device__ __forceinline__ void split2(float f, unsigned short& hi, unsigned short& lo) {
  hi = f2bf(f);
  lo = f2bf(f - bf2f(hi));
}

// ---------------------------------------------------------------------------
// P0: transpose+convert w_qkv (256 x 1536 f32) -> wThi/wTlo (1536 x 256 bf16).
// Also zeroes ctx_un+Ssum (replaces a separate memset dispatch; stream order
// guarantees completion before K1).
// ---------------------------------------------------------------------------
__global__ __launch_bounds__(256) void prep_wT(
    const float* __restrict__ wqkv, unsigned short* __restrict__ wThi,
    unsigned short* __restrict__ wTlo, float* __restrict__ zero_base)
{
  __shared__ __align__(16) unsigned short thi[64][68];
  __shared__ __align__(16) unsigned short tlo[64][68];
  const int tid = threadIdx.x;
  const int f0 = (blockIdx.x >> 2) * 64;
  const int k0 = (blockIdx.x & 3) * 64;

  // ---- zero ctx_un + Ssum (exactly 16640 float4s over 96*256 threads) ----
  {
    const int gid = blockIdx.x * 256 + tid;
    if (gid < ZERO_F4)
      ((float4*)zero_base)[gid] = make_float4(0.f, 0.f, 0.f, 0.f);
  }

  {
    const int kl = tid >> 2;          // 0..63
    const int fc = (tid & 3) * 16;
#pragma unroll
    for (int i = 0; i < 4; ++i) {
      const float4 v = *(const float4*)(wqkv + (size_t)(k0 + kl) * (3 * DIM) + f0 + fc + i * 4);
      unsigned short h, l;
      split2(v.x, h, l); thi[kl][fc + i*4 + 0] = h; tlo[kl][fc + i*4 + 0] = l;
      split2(v.y, h, l); thi[kl][fc + i*4 + 1] = h; tlo[kl][fc + i*4 + 1] = l;
      split2(v.z, h, l); thi[kl][fc + i*4 + 2] = h; tlo[kl][fc + i*4 + 2] = l;
      split2(v.w, h, l); thi[kl][fc + i*4 + 3] = h; tlo[kl][fc + i*4 + 3] = l;
    }
  }
  __syncthreads();
  {
    const int fl = tid >> 2;          // 0..63
    const int kc = (tid & 3) * 16;
    unsigned int ph[8], pl[8];
#pragma unroll
    for (int m = 0; m < 8; ++m) {
      ph[m] = (unsigned)thi[kc + 2*m][fl] | ((unsigned)thi[kc + 2*m + 1][fl] << 16);
      pl[m] = (unsigned)tlo[kc + 2*m][fl] | ((unsigned)tlo[kc + 2*m + 1][fl] << 16);
    }
    unsigned int* dh = (unsigned int*)(wThi + (size_t)(f0 + fl) * CIN + k0 + kc);
    unsigned int* dl = (unsigned int*)(wTlo + (size_t)(f0 + fl) * CIN + k0 + kc);
#pragma unroll
    for (int m = 0; m < 8; ++m) { dh[m] = ph[m]; dl[m] = pl[m]; }
  }
}

// ---------------------------------------------------------------------------
// K1: split-bf16 k/v projection (MFMA) + split-bf16 ctx += E^T V (MFMA).
// grid = BATCH*HEADS*NB = 1024 blocks, 256 threads (4 waves).
// XCD swizzle: tb = L[8:6]*8 | L[2:0], h = L[5:3], b = L[9] -> XCD(=L%8)=tb&7:
// the 8 heads of one (b, token-range) share an XCD -> x tile hits its L2.
// Waves 0,1 -> k cols (write exp(k) split, transposed), 2,3 -> v cols.
// Then all waves: ctx[d][e] += sum_t ek[t,d]*v[t,e] via 16x16x32 MFMAs,
// and S[d] += sum_t ek[t,d] via a B=ones MFMA.
// ---------------------------------------------------------------------------
__global__ __launch_bounds__(256, 2) void kv_ctx_mfma(
    const float* __restrict__ x,
    const unsigned short* __restrict__ wThi, const unsigned short* __restrict__ wTlo,
    float* __restrict__ ctx_un, float* __restrict__ Ssum)
{
  __shared__ __align__(16) unsigned short xhi[32 * XPAD];   // 16.9 KB
  __shared__ __align__(16) unsigned short xlo[32 * XPAD];   // 16.9 KB
  __shared__ __align__(16) unsigned short ekhi[64 * TP];    // 5.1 KB
  __shared__ __align__(16) unsigned short eklo[64 * TP];
  __shared__ __align__(16) unsigned short vhs[64 * TP];
  __shared__ __align__(16) unsigned short vls[64 * TP];

  const int tid = threadIdx.x;
  const int L = blockIdx.x;
  const int tb = (((L >> 6) & 7) << 3) | (L & 7);  // 0..63
  const int h  = (L >> 3) & 7;
  const int b  = L >> 9;
  const int TOKENS = NTOK / NB;     // 512 (compile-time)
  const int n0 = tb * TOKENS;

  const int wave = tid >> 6;
  const int lane = tid & 63;
  const int lg = lane >> 4;         // 0..3
  const int lr = lane & 15;

  const bool isv = wave >= 2;
  const int cbase = (wave & 1) * 32;                     // local col base
  const int wrow_base = (isv ? 2 * DIM : DIM) + h * DH + cbase;

  // register-resident B-frags (hi/lo): 2 col-tiles x 8 k-steps
  bf16x8 bh[2][8], bl[2][8];
#pragma unroll
  for (int ct = 0; ct < 2; ++ct) {
    const size_t row = (size_t)(wrow_base + ct * 16 + lr);
#pragma unroll
    for (int kk = 0; kk < 8; ++kk) {
      bh[ct][kk] = *(const bf16x8*)(wThi + row * CIN + kk * 32 + lg * 8);
      bl[ct][kk] = *(const bf16x8*)(wTlo + row * CIN + kk * 32 + lg * 8);
    }
  }

  const short one_bf = (short)0x3F80;
  const bf16x8 bones = {one_bf, one_bf, one_bf, one_bf, one_bf, one_bf, one_bf, one_bf};

  f32x4 ctx[4];
#pragma unroll
  for (int et = 0; et < 4; ++et) ctx[et] = (f32x4)0.f;
  f32x4 acc_s = (f32x4)0.f;

#pragma unroll 1
  for (int sub = 0; sub < TOKENS / 32; ++sub) {
    const int nbase = n0 + sub * 32;
    // ---- stage 32x256 x tile as split bf16 ----
    {
      const int row = tid >> 3;
      const int c0f = (tid & 7) * 32;
      const float4* xg = (const float4*)(x + ((size_t)b * NTOK + nbase) * CIN);
      unsigned short* dh = xhi + row * XPAD + c0f;
      unsigned short* dl = xlo + row * XPAD + c0f;
#pragma unroll
      for (int i = 0; i < 8; ++i) {
        const float4 v = xg[row * 64 + (c0f >> 2) + i];
        unsigned short h0,l0,h1,l1,h2,l2,h3,l3;
        split2(v.x,h0,l0); split2(v.y,h1,l1); split2(v.z,h2,l2); split2(v.w,h3,l3);
        *(uint2*)(dh + i*4) = make_uint2((unsigned)h0 | ((unsigned)h1 << 16),
                                         (unsigned)h2 | ((unsigned)h3 << 16));
        *(uint2*)(dl + i*4) = make_uint2((unsigned)l0 | ((unsigned)l1 << 16),
                                         (unsigned)l2 | ((unsigned)l3 << 16));
      }
    }
    __syncthreads();   // stage done; also protects ekT/vT overwrite vs prev ctx reads

    // ---- projection: 32 tokens x 32 cols per wave, K=256, split-bf16 ----
    f32x4 acc[2][2];
#pragma unroll
    for (int rt = 0; rt < 2; ++rt)
#pragma unroll
      for (int ct = 0; ct < 2; ++ct) acc[rt][ct] = (f32x4)0.f;

#pragma unroll
    for (int kk = 0; kk < 8; ++kk) {
      const bf16x8 a0h = *(const bf16x8*)(xhi + (0 + lr) * XPAD + kk * 32 + lg * 8);
      const bf16x8 a1h = *(const bf16x8*)(xhi + (16 + lr) * XPAD + kk * 32 + lg * 8);
      const bf16x8 a0l = *(const bf16x8*)(xlo + (0 + lr) * XPAD + kk * 32 + lg * 8);
      const bf16x8 a1l = *(const bf16x8*)(xlo + (16 + lr) * XPAD + kk * 32 + lg * 8);
#pragma unroll
      for (int ct = 0; ct < 2; ++ct) {
        acc[0][ct] = mfma16(a0h, bh[ct][kk], acc[0][ct]);
        acc[0][ct] = mfma16(a0h, bl[ct][kk], acc[0][ct]);
        acc[0][ct] = mfma16(a0l, bh[ct][kk], acc[0][ct]);
        acc[1][ct] = mfma16(a1h, bh[ct][kk], acc[1][ct]);
        acc[1][ct] = mfma16(a1h, bl[ct][kk], acc[1][ct]);
        acc[1][ct] = mfma16(a1l, bh[ct][kk], acc[1][ct]);
      }
    }

    // ---- split + transposed scatter: ekT/vT[c][t] (b64-packed 4 t's) ----
#pragma unroll
    for (int rt = 0; rt < 2; ++rt)
#pragma unroll
      for (int ct = 0; ct < 2; ++ct) {
        unsigned short hh[4], ll[4];
#pragma unroll
        for (int r = 0; r < 4; ++r) {
          float f = acc[rt][ct][r];
          if (!isv) f = __expf(f);
          split2(f, hh[r], ll[r]);
        }
        const int c = cbase + ct * 16 + lr;
        const int t0 = rt * 16 + lg * 4;
        unsigned short* ph = (isv ? vhs : ekhi) + c * TP + t0;
        unsigned short* pl = (isv ? vls : eklo) + c * TP + t0;
        *(uint2*)ph = make_uint2((unsigned)hh[0] | ((unsigned)hh[1] << 16),
                                 (unsigned)hh[2] | ((unsigned)hh[3] << 16));
        *(uint2*)pl = make_uint2((unsigned)ll[0] | ((unsigned)ll[1] << 16),
                                 (unsigned)ll[2] | ((unsigned)ll[3] << 16));
      }
    __syncthreads();

    // ---- ctx += E^T V (split-bf16), S += E^T 1 ----
    {
      const int drow = wave * 16 + lr;
      const bf16x8 aeh = *(const bf16x8*)(ekhi + drow * TP + lg * 8);
      const bf16x8 ael = *(const bf16x8*)(eklo + drow * TP + lg * 8);
      acc_s = mfma16(aeh, bones, acc_s);
      acc_s = mfma16(ael, bones, acc_s);
#pragma unroll
      for (int et = 0; et < 4; ++et) {
        const bf16x8 bvh = *(const bf16x8*)(vhs + (et * 16 + lr) * TP + lg * 8);
        const bf16x8 bvl = *(const bf16x8*)(vls + (et * 16 + lr) * TP + lg * 8);
        ctx[et] = mfma16(aeh, bvh, ctx[et]);
        ctx[et] = mfma16(aeh, bvl, ctx[et]);
        ctx[et] = mfma16(ael, bvh, ctx[et]);
      }
    }
  }

  float* ctxb = ctx_un + ((size_t)b * HEADS + h) * DH * DH;
#pragma unroll
  for (int et = 0; et < 4; ++et)
#pragma unroll
    for (int r = 0; r < 4; ++r)
      atomicAdd(&ctxb[(wave * 16 + lg * 4 + r) * DH + et * 16 + lr], ctx[et][r]);
  if (lr == 0) {
#pragma unroll
    for (int r = 0; r < 4; ++r)
      atomicAdd(&Ssum[((size_t)b * HEADS + h) * DH + wave * 16 + lg * 4 + r], acc_s[r]);
  }
}

// ---------------------------------------------------------------------------
// K2: MT[b][c][f] = split_bf16( sum_e ctx[h,d,e]*(invN/S[d]) * w_out[h*64+e][c] )
// ---------------------------------------------------------------------------
__global__ __launch_bounds__(256) void m_kernel(
    const float* __restrict__ ctx_un, const float* __restrict__ Ssum,
    const float* __restrict__ wout, unsigned short* __restrict__ MThi,
    unsigned short* __restrict__ MTlo, float invN)
{
  const int blk = blockIdx.x;
  const int b = blk >> 5;
  const int f0 = (blk & 31) * 16;
  const int h = f0 / DH;
  const int c = threadIdx.x;
  const float* ctxb = ctx_un + ((size_t)b * HEADS + h) * DH * DH;
  const float* Sb   = Ssum + ((size_t)b * HEADS + h) * DH;
  float acc[16];
#pragma unroll
  for (int i = 0; i < 16; ++i) acc[i] = 0.f;
  for (int e = 0; e < DH; ++e) {
    const float wv = wout[(size_t)(h * DH + e) * CIN + c];
#pragma unroll
    for (int i = 0; i < 16; ++i) {
      const int d = (f0 + i) & (DH - 1);
      acc[i] += ctxb[d * DH + e] * wv;
    }
  }
  unsigned short* mh = MThi + ((size_t)b * CIN + c) * DIM;
  unsigned short* ml = MTlo + ((size_t)b * CIN + c) * DIM;
#pragma unroll
  for (int i = 0; i < 16; ++i) {
    const int d = (f0 + i) & (DH - 1);
    unsigned short hh, ll;
    split2(acc[i] * (invN / Sb[d]), hh, ll);
    mh[f0 + i] = hh;
    ml[f0 + i] = ll;
  }
}

// ---------------------------------------------------------------------------
// K3: per 32-token tile: q = x@wq (split MFMA); in-register head softmax (/8);
// y = q_soft @ M (split MFMA, two K=256 passes, q chunks reuse x LDS);
// +bias; LayerNorm; store. grid = BATCH*NTOK/32, 256 threads.
// ---------------------------------------------------------------------------
__global__ __launch_bounds__(256, 2) void out_mfma(
    const float* __restrict__ x,
    const unsigned short* __restrict__ wThi, const unsigned short* __restrict__ wTlo,
    const unsigned short* __restrict__ MThi, const unsigned short* __restrict__ MTlo,
    const float* __restrict__ bout, const float* __restrict__ lnsc,
    float* __restrict__ out)
{
  __shared__ __align__(16) unsigned short ldsA[2 * 32 * XPAD];  // x hi/lo -> q-chunk hi/lo
  __shared__ float red[4][32][2];
  __shared__ float mus[32], rss[32];

  unsigned short* const xh = ldsA;
  unsigned short* const xl = ldsA + 32 * XPAD;
  unsigned short* const qh = ldsA;              // after GEMM1 (x dead)
  unsigned short* const ql = ldsA + 32 * XPAD;

  const int tid = threadIdx.x;
  const int blk = blockIdx.x;
  const int blocks_per_b = NTOK / 32;
  const int b = blk / blocks_per_b;
  const int n0 = (blk % blocks_per_b) * 32;

  const int wave = tid >> 6;
  const int lane = tid & 63;
  const int lg = lane >> 4;
  const int lr = lane & 15;

  // ---- stage x split ----
  {
    const int row = tid >> 3;
    const int c0f = (tid & 7) * 32;
    const float4* xg = (const float4*)(x + ((size_t)b * NTOK + n0) * CIN);
    unsigned short* dh = xh + row * XPAD + c0f;
    unsigned short* dl = xl + row * XPAD + c0f;
#pragma unroll
    for (int i = 0; i < 8; ++i) {
      const float4 v = xg[row * 64 + (c0f >> 2) + i];
      unsigned short h0,l0,h1,l1,h2,l2,h3,l3;
      split2(v.x,h0,l0); split2(v.y,h1,l1); split2(v.z,h2,l2); split2(v.w,h3,l3);
      *(uint2*)(dh + i*4) = make_uint2((unsigned)h0 | ((unsigned)h1 << 16),
                                       (unsigned)h2 | ((unsigned)h3 << 16));
      *(uint2*)(dl + i*4) = make_uint2((unsigned)l0 | ((unsigned)l1 << 16),
                                       (unsigned)l2 | ((unsigned)l3 << 16));
    }
  }
  __syncthreads();

  // ---- GEMM1: q(32x512) split, wave w -> cols w*128..+127 ----
  f32x4 q[2][8];
#pragma unroll
  for (int rt = 0; rt < 2; ++rt)
#pragma unroll
    for (int ct = 0; ct < 8; ++ct) q[rt][ct] = (f32x4)0.f;

#pragma unroll 2
  for (int kk = 0; kk < 8; ++kk) {
    const bf16x8 a0h = *(const bf16x8*)(xh + (0 + lr) * XPAD + kk * 32 + lg * 8);
    const bf16x8 a1h = *(const bf16x8*)(xh + (16 + lr) * XPAD + kk * 32 + lg * 8);
    const bf16x8 a0l = *(const bf16x8*)(xl + (0 + lr) * XPAD + kk * 32 + lg * 8);
    const bf16x8 a1l = *(const bf16x8*)(xl + (16 + lr) * XPAD + kk * 32 + lg * 8);
#pragma unroll
    for (int ct = 0; ct < 8; ++ct) {
      const size_t row = (size_t)(wave * 128 + ct * 16 + lr);
      const bf16x8 bwh = *(const bf16x8*)(wThi + row * CIN + kk * 32 + lg * 8);
      const bf16x8 bwl = *(const bf16x8*)(wTlo + row * CIN + kk * 32 + lg * 8);
      q[0][ct] = mfma16(a0h, bwh, q[0][ct]);
      q[0][ct] = mfma16(a0h, bwl, q[0][ct]);
      q[0][ct] = mfma16(a0l, bwh, q[0][ct]);
      q[1][ct] = mfma16(a1h, bwh, q[1][ct]);
      q[1][ct] = mfma16(a1h, bwl, q[1][ct]);
      q[1][ct] = mfma16(a1l, bwh, q[1][ct]);
    }
  }

  // ---- in-register softmax per (token, head), then *1/8 ----
#pragma unroll
  for (int rt = 0; rt < 2; ++rt)
#pragma unroll
    for (int hg = 0; hg < 2; ++hg)
#pragma unroll
      for (int r = 0; r < 4; ++r) {
        float m0 = fmaxf(fmaxf(q[rt][hg*4+0][r], q[rt][hg*4+1][r]),
                         fmaxf(q[rt][hg*4+2][r], q[rt][hg*4+3][r]));
#pragma unroll
        for (int off = 1; off < 16; off <<= 1)
          m0 = fmaxf(m0, __shfl_xor(m0, off, 16));
        const float e0v = __expf(q[rt][hg*4+0][r] - m0);
        const float e1v = __expf(q[rt][hg*4+1][r] - m0);
        const float e2v = __expf(q[rt][hg*4+2][r] - m0);
        const float e3v = __expf(q[rt][hg*4+3][r] - m0);
        float s = e0v + e1v + e2v + e3v;
#pragma unroll
        for (int off = 1; off < 16; off <<= 1)
          s += __shfl_xor(s, off, 16);
        const float sc = 0.125f / s;
        q[rt][hg*4+0][r] = e0v * sc;
        q[rt][hg*4+1][r] = e1v * sc;
        q[rt][hg*4+2][r] = e2v * sc;
        q[rt][hg*4+3][r] = e3v * sc;
      }

  __syncthreads();   // all x reads done -> ldsA reusable for q chunks

  // ---- waves 0,1 write q cols 0..255 (split) ----
  if (wave < 2) {
#pragma unroll
    for (int rt = 0; rt < 2; ++rt)
#pragma unroll
      for (int ct = 0; ct < 8; ++ct)
#pragma unroll
        for (int r = 0; r < 4; ++r) {
          const int t = rt * 16 + lg * 4 + r;
          const int col = wave * 128 + ct * 16 + lr;
          unsigned short hh, ll;
          split2(q[rt][ct][r], hh, ll);
          qh[t * XPAD + col] = hh;
          ql[t * XPAD + col] = ll;
        }
  }
  __syncthreads();

  // ---- GEMM2 in two K=256 passes ----
  f32x4 y[2][4];
#pragma unroll
  for (int rt = 0; rt < 2; ++rt)
#pragma unroll
    for (int ct = 0; ct < 4; ++ct) y[rt][ct] = (f32x4)0.f;

  const unsigned short* mhB = MThi + (size_t)b * CIN * DIM;
  const unsigned short* mlB = MTlo + (size_t)b * CIN * DIM;

#pragma unroll
  for (int pass = 0; pass < 2; ++pass) {
    const int fofs = pass * 256;
#pragma unroll 2
    for (int kk = 0; kk < 8; ++kk) {
      const bf16x8 a0h = *(const bf16x8*)(qh + (0 + lr) * XPAD + kk * 32 + lg * 8);
      const bf16x8 a1h = *(const bf16x8*)(qh + (16 + lr) * XPAD + kk * 32 + lg * 8);
      const bf16x8 a0l = *(const bf16x8*)(ql + (0 + lr) * XPAD + kk * 32 + lg * 8);
      const bf16x8 a1l = *(const bf16x8*)(ql + (16 + lr) * XPAD + kk * 32 + lg * 8);
#pragma unroll
      for (int ct = 0; ct < 4; ++ct) {
        const size_t crow = (size_t)(wave * 64 + ct * 16 + lr);
        const bf16x8 bmh = *(const bf16x8*)(mhB + crow * DIM + fofs + kk * 32 + lg * 8);
        const bf16x8 bml = *(const bf16x8*)(mlB + crow * DIM + fofs + kk * 32 + lg * 8);
        y[0][ct] = mfma16(a0h, bmh, y[0][ct]);
        y[0][ct] = mfma16(a0h, bml, y[0][ct]);
        y[0][ct] = mfma16(a0l, bmh, y[0][ct]);
        y[1][ct] = mfma16(a1h, bmh, y[1][ct]);
        y[1][ct] = mfma16(a1h, bml, y[1][ct]);
        y[1][ct] = mfma16(a1l, bmh, y[1][ct]);
      }
    }
    if (pass == 0) {
      __syncthreads();   // pass-0 q reads done
      if (wave >= 2) {   // waves 2,3 write q cols 256..511
#pragma unroll
        for (int rt = 0; rt < 2; ++rt)
#pragma unroll
          for (int ct = 0; ct < 8; ++ct)
#pragma unroll
            for (int r = 0; r < 4; ++r) {
              const int t = rt * 16 + lg * 4 + r;
              const int col = wave * 128 + ct * 16 + lr - 256;
              unsigned short hh, ll;
              split2(q[rt][ct][r], hh, ll);
              qh[t * XPAD + col] = hh;
              ql[t * XPAD + col] = ll;
            }
      }
      __syncthreads();
    }
  }

  // ---- +bias ----
#pragma unroll
  for (int ct = 0; ct < 4; ++ct) {
    const float bb = bout[wave * 64 + ct * 16 + lr];
#pragma unroll
    for (int rt = 0; rt < 2; ++rt)
#pragma unroll
      for (int r = 0; r < 4; ++r) y[rt][ct][r] += bb;
  }

  // ---- LN stats ----
#pragma unroll
  for (int rt = 0; rt < 2; ++rt)
#pragma unroll
    for (int r = 0; r < 4; ++r) {
      float ps = y[rt][0][r] + y[rt][1][r] + y[rt][2][r] + y[rt][3][r];
      float ps2 = y[rt][0][r]*y[rt][0][r] + y[rt][1][r]*y[rt][1][r]
                + y[rt][2][r]*y[rt][2][r] + y[rt][3][r]*y[rt][3][r];
#pragma unroll
      for (int off = 1; off < 16; off <<= 1) {
        ps  += __shfl_xor(ps,  off, 16);
        ps2 += __shfl_xor(ps2, off, 16);
      }
      if (lr == 0) {
        const int t = rt * 16 + lg * 4 + r;
        red[wave][t][0] = ps;
        red[wave][t][1] = ps2;
      }
    }
  __syncthreads();
  if (tid < 32) {
    const float S1 = red[0][tid][0] + red[1][tid][0] + red[2][tid][0] + red[3][tid][0];
    const float S2 = red[0][tid][1] + red[1][tid][1] + red[2][tid][1] + red[3][tid][1];
    const float mu = S1 * (1.f / CIN);
    const float var = S2 * (1.f / CIN) - mu * mu;
    mus[tid] = mu;
    rss[tid] = rsqrtf(var + EPS);
  }
  __syncthreads();

  // ---- normalize + scale + store ----
  float* ob = out + ((size_t)b * NTOK + n0) * CIN;
#pragma unroll
  for (int ct = 0; ct < 4; ++ct) {
    const int c = wave * 64 + ct * 16 + lr;
    const float lsc = lnsc[c];
#pragma unroll
    for (int rt = 0; rt < 2; ++rt)
#pragma unroll
      for (int r = 0; r < 4; ++r) {
        const int t = rt * 16 + lg * 4 + r;
        ob[(size_t)t * CIN + c] = (y[rt][ct][r] - mus[t]) * rss[t] * lsc;
      }
  }
}

// ---------------------------------------------------------------------------
extern "C" void kernel_launch(void* const* d_in, const int* in_sizes, int n_in,
                              void* d_out, int out_size, void* d_ws, size_t ws_size,
                              hipStream_t stream) {
  const float* x     = (const float*)d_in[0];
  const float* wqkv  = (const float*)d_in[1];
  const float* wout  = (const float*)d_in[2];
  const float* bout  = (const float*)d_in[3];
  const float* lnsc  = (const float*)d_in[4];
  float* out = (float*)d_out;

  unsigned short* wThi = (unsigned short*)d_ws;               // 1536*256
  unsigned short* wTlo = wThi + (size_t)(3 * DIM) * CIN;
  unsigned short* MThi = wTlo + (size_t)(3 * DIM) * CIN;      // B*256*512
  unsigned short* MTlo = MThi + (size_t)BATCH * CIN * DIM;
  float* ctx_un = (float*)(MTlo + (size_t)BATCH * CIN * DIM); // B*8*64*64
  float* Ssum   = ctx_un + (size_t)BATCH * HEADS * DH * DH;   // B*8*64 (contiguous after ctx_un)

  prep_wT<<<dim3(96), dim3(256), 0, stream>>>(wqkv, wThi, wTlo, ctx_un);
  kv_ctx_mfma<<<dim3(BATCH * HEADS * NB), dim3(256), 0, stream>>>(
      x, wThi, wTlo, ctx_un, Ssum);
  m_kernel<<<dim3(BATCH * 32), dim3(256), 0, stream>>>(
      ctx_un, Ssum, wout, MThi, MTlo, 1.0f / (float)NTOK);
  out_mfma<<<dim3(BATCH * (NTOK / 32)), dim3(256), 0, stream>>>(
      x, wThi, wTlo, MThi, MTlo, bout, lnsc, out);
}